// Round 1
// baseline (6626.408 us; speedup 1.0000x reference)
//
#include <hip/hip_runtime.h>
#include <math.h>

// Problem constants (fixed by the reference)
#define B_  2
#define S_  2048
#define D_  2048
#define H_  16
#define HD_ 128
#define L_  512
constexpr float EPS   = 1e-5f;
constexpr float SCALE = 0.08838834764831845f; // 1/sqrt(128)

// ---------------------------------------------------------------------------
// GEMM: C[M,N] = A[M,K] @ W[K,N] + bias[N]   (all row-major fp32)
// 64x64 block tile, K-tile 16, 256 threads, 4x4 per-thread micro-tile.
// LDS padded to 68 floats/row: 16B-aligned float4 reads, conflict-free stores.
// Requires M%64==0, N%64==0, K%16==0 (true for all shapes here).
// ---------------------------------------------------------------------------
__global__ __launch_bounds__(256)
void gemm_bias_kernel(const float* __restrict__ A, const float* __restrict__ W,
                      const float* __restrict__ bias, float* __restrict__ C,
                      int M, int N, int K) {
    __shared__ __align__(16) float As[16][68];
    __shared__ __align__(16) float Bs[16][68];

    const int tid = threadIdx.x;
    const int tx  = tid & 15;   // micro-tile col group
    const int ty  = tid >> 4;   // micro-tile row group
    const int m0  = blockIdx.y * 64;
    const int n0  = blockIdx.x * 64;

    // A-load mapping: thread loads A[m0 + a_tm + 16*i][kt + a_tk]
    const int a_tk = tid & 15;
    const int a_tm = tid >> 4;
    // B-load mapping: thread loads W[kt + b_tk + 4*j][n0 + b_tn]
    const int b_tn = tid & 63;
    const int b_tk = tid >> 6;

    float acc[4][4] = {};

    for (int kt = 0; kt < K; kt += 16) {
#pragma unroll
        for (int i = 0; i < 4; ++i)
            As[a_tk][a_tm + 16 * i] =
                A[(size_t)(m0 + a_tm + 16 * i) * K + kt + a_tk];
#pragma unroll
        for (int j = 0; j < 4; ++j)
            Bs[b_tk + 4 * j][b_tn] =
                W[(size_t)(kt + b_tk + 4 * j) * N + n0 + b_tn];
        __syncthreads();

#pragma unroll
        for (int kk = 0; kk < 16; ++kk) {
            float4 av = *(const float4*)&As[kk][ty * 4];
            float4 bv = *(const float4*)&Bs[kk][tx * 4];
            float a_[4] = {av.x, av.y, av.z, av.w};
            float b_[4] = {bv.x, bv.y, bv.z, bv.w};
#pragma unroll
            for (int i = 0; i < 4; ++i)
#pragma unroll
                for (int j = 0; j < 4; ++j)
                    acc[i][j] += a_[i] * b_[j];
        }
        __syncthreads();
    }

#pragma unroll
    for (int i = 0; i < 4; ++i) {
        const int m = m0 + ty * 4 + i;
#pragma unroll
        for (int j = 0; j < 4; ++j) {
            const int n = n0 + tx * 4 + j;
            C[(size_t)m * N + n] = acc[i][j] + bias[n];
        }
    }
}

// ---------------------------------------------------------------------------
// In-place row LayerNorm over rows of length 512. One block (256 thr) per row.
// y = (x - mean) * rsqrt(var + eps) * g + b      (population variance)
// ---------------------------------------------------------------------------
__global__ __launch_bounds__(256)
void layernorm512_kernel(float* __restrict__ buf, const float* __restrict__ g,
                         const float* __restrict__ bvec) {
    const int row = blockIdx.x;
    float* p = buf + (size_t)row * L_;
    const int tid = threadIdx.x;

    float x0 = p[tid], x1 = p[tid + 256];
    float s  = x0 + x1;
    float sq = x0 * x0 + x1 * x1;

    __shared__ float red[8];
    __shared__ float stats[2];

#pragma unroll
    for (int off = 32; off; off >>= 1) {
        s  += __shfl_down(s, off);
        sq += __shfl_down(sq, off);
    }
    const int wave = tid >> 6;
    if ((tid & 63) == 0) { red[wave] = s; red[wave + 4] = sq; }
    __syncthreads();
    if (tid == 0) {
        float ts = red[0] + red[1] + red[2] + red[3];
        float tq = red[4] + red[5] + red[6] + red[7];
        float mean = ts / (float)L_;
        float var  = tq / (float)L_ - mean * mean;
        stats[0] = mean;
        stats[1] = rsqrtf(var + EPS);
    }
    __syncthreads();
    const float mean = stats[0], rstd = stats[1];
    p[tid]       = (x0 - mean) * rstd * g[tid]       + bvec[tid];
    p[tid + 256] = (x1 - mean) * rstd * g[tid + 256] + bvec[tid + 256];
}

// ---------------------------------------------------------------------------
// Causal attention, two-pass softmax per query row.
// One block (256 thr) per (b, h, qi). Scores row staged in LDS (8 KB).
// q: [B*S, D] (head-interleaved) — ALSO the output (written in place; each
// block reads only its own q row, copied to LDS before the final write).
// kv: [B*S, 2D], K = cols [h*HD, h*HD+HD), V = cols [D + h*HD, ...).
// ---------------------------------------------------------------------------
__global__ __launch_bounds__(256)
void attn_kernel(float* __restrict__ q, const float* __restrict__ kv,
                 const unsigned char* __restrict__ mask) {
    const int idx = blockIdx.x;          // (b*H + h)*S + qi
    const int qi  = idx & (S_ - 1);
    const int h   = (idx >> 11) & (H_ - 1);
    const int b   = idx >> 15;
    const int tid = threadIdx.x;

    __shared__ float sc[S_];             // 8 KB score row
    __shared__ __align__(16) float qv[HD_];
    __shared__ float part[256];
    __shared__ float red[8];
    __shared__ float stats[2];

    float* qrow = q + ((size_t)(b * S_ + qi) * D_ + h * HD_);
    if (tid < HD_) qv[tid] = qrow[tid];
    __syncthreads();

    const int nk = qi + 1;               // causal: keys 0..qi

    // Phase 1: scores
    for (int k = tid; k < nk; k += 256) {
        const float* krow = kv + ((size_t)(b * S_ + k) * (2 * D_) + h * HD_);
        float s = 0.f;
#pragma unroll 8
        for (int d = 0; d < HD_; d += 4) {
            float4 kf = *(const float4*)(krow + d);
            float4 qf = *(const float4*)(qv + d);
            s += kf.x * qf.x + kf.y * qf.y + kf.z * qf.z + kf.w * qf.w;
        }
        s *= SCALE;
        if (mask[b * S_ + k]) s = -INFINITY;
        sc[k] = s;
    }
    __syncthreads();

    // Phase 2a: row max
    float m = -INFINITY;
    for (int k = tid; k < nk; k += 256) m = fmaxf(m, sc[k]);
#pragma unroll
    for (int off = 32; off; off >>= 1) m = fmaxf(m, __shfl_down(m, off));
    if ((tid & 63) == 0) red[tid >> 6] = m;
    __syncthreads();
    if (tid == 0)
        stats[0] = fmaxf(fmaxf(red[0], red[1]), fmaxf(red[2], red[3]));
    __syncthreads();
    m = stats[0];

    // Phase 2b: exp + sum
    float s = 0.f;
    for (int k = tid; k < nk; k += 256) {
        float p = expf(sc[k] - m);
        sc[k] = p;
        s += p;
    }
#pragma unroll
    for (int off = 32; off; off >>= 1) s += __shfl_down(s, off);
    if ((tid & 63) == 0) red[tid >> 6] = s;
    __syncthreads();
    if (tid == 0) stats[1] = red[0] + red[1] + red[2] + red[3];
    __syncthreads();
    const float inv = 1.f / stats[1];

    // Phase 3: out[d] = sum_k p[k] * V[k][d]  (two threads per d, halves of k)
    const int d    = tid & (HD_ - 1);
    const int half = tid >> 7;
    float acc = 0.f;
    for (int k = half; k < nk; k += 2)
        acc += sc[k] * kv[(size_t)(b * S_ + k) * (2 * D_) + D_ + h * HD_ + d];
    part[tid] = acc;
    __syncthreads();
    if (tid < HD_) qrow[tid] = (part[tid] + part[tid + 128]) * inv;
}

// ---------------------------------------------------------------------------
extern "C" void kernel_launch(void* const* d_in, const int* in_sizes, int n_in,
                              void* d_out, int out_size, void* d_ws, size_t ws_size,
                              hipStream_t stream) {
    const float* x        = (const float*)d_in[0];
    const unsigned char* mask = (const unsigned char*)d_in[1];
    const float* wq_down  = (const float*)d_in[2];
    const float* bq_down  = (const float*)d_in[3];
    const float* gq_ln    = (const float*)d_in[4];
    const float* bq_ln    = (const float*)d_in[5];
    const float* wq_up    = (const float*)d_in[6];
    const float* bq_up    = (const float*)d_in[7];
    const float* wkv_down = (const float*)d_in[8];
    const float* bkv_down = (const float*)d_in[9];
    const float* gkv_ln   = (const float*)d_in[10];
    const float* bkv_ln   = (const float*)d_in[11];
    const float* wkv_up   = (const float*)d_in[12];
    const float* bkv_up   = (const float*)d_in[13];
    const float* w_out    = (const float*)d_in[14];
    const float* b_out    = (const float*)d_in[15];
    float* out = (float*)d_out;

    // Workspace layout (floats): q_lat[4096x512] kv_lat[4096x512]
    //                            q[4096x2048] (becomes attn out) kv[4096x4096]
    float* ws     = (float*)d_ws;
    float* q_lat  = ws;
    float* kv_lat = ws + (size_t)2097152;
    float* q      = ws + (size_t)4194304;
    float* kv     = ws + (size_t)12582912;

    const int M = B_ * S_;  // 4096
    dim3 blk(256);

    // Q path: down-proj -> LN -> up-proj
    gemm_bias_kernel<<<dim3(L_ / 64, M / 64), blk, 0, stream>>>(
        x, wq_down, bq_down, q_lat, M, L_, D_);
    layernorm512_kernel<<<M, blk, 0, stream>>>(q_lat, gq_ln, bq_ln);
    gemm_bias_kernel<<<dim3(D_ / 64, M / 64), blk, 0, stream>>>(
        q_lat, wq_up, bq_up, q, M, D_, L_);

    // KV path: down-proj -> LN -> up-proj (K|V fused in one [M, 2D] buffer)
    gemm_bias_kernel<<<dim3(L_ / 64, M / 64), blk, 0, stream>>>(
        x, wkv_down, bkv_down, kv_lat, M, L_, D_);
    layernorm512_kernel<<<M, blk, 0, stream>>>(kv_lat, gkv_ln, bkv_ln);
    gemm_bias_kernel<<<dim3((2 * D_) / 64, M / 64), blk, 0, stream>>>(
        kv_lat, wkv_up, bkv_up, kv, M, 2 * D_, L_);

    // Attention: writes head outputs in place over q
    attn_kernel<<<B_ * H_ * S_, blk, 0, stream>>>(q, kv, mask);

    // Output projection
    gemm_bias_kernel<<<dim3(D_ / 64, M / 64), blk, 0, stream>>>(
        q, w_out, b_out, out, M, D_, D_);
}

// Round 2
// 1540.180 us; speedup vs baseline: 4.3024x; 4.3024x over previous
//
#include <hip/hip_runtime.h>
#include <math.h>
#include <type_traits>

typedef unsigned short u16;

// Problem constants (fixed by the reference)
#define B_  2
#define S_  2048
#define D_  2048
#define H_  16
#define HD_ 128
#define L_  512
constexpr float EPS   = 1e-5f;
constexpr float SCALE = 0.08838834764831845f; // 1/sqrt(128)

typedef __attribute__((ext_vector_type(8))) short bf16x8;
typedef __attribute__((ext_vector_type(4))) float f32x4;

__device__ __forceinline__ u16 f2bf(float x) {
    unsigned u = __float_as_uint(x);
    u += 0x7fffu + ((u >> 16) & 1u);   // round-to-nearest-even
    return (u16)(u >> 16);
}

// ---------------------------------------------------------------------------
// GEMM: C[M,N] = A[M,K] @ W[K,N] + bias[N]  (fp32 compute, OutT output)
// 64x64 tile, K-tile 16, 256 threads, 4x4 micro-tile.
// ---------------------------------------------------------------------------
template <typename OutT>
__global__ __launch_bounds__(256)
void gemm_bias_kernel(const float* __restrict__ A, const float* __restrict__ W,
                      const float* __restrict__ bias, OutT* __restrict__ C,
                      int M, int N, int K) {
    __shared__ __align__(16) float As[16][68];
    __shared__ __align__(16) float Bs[16][68];

    const int tid = threadIdx.x;
    const int tx  = tid & 15;
    const int ty  = tid >> 4;
    const int m0  = blockIdx.y * 64;
    const int n0  = blockIdx.x * 64;

    const int a_tk = tid & 15;
    const int a_tm = tid >> 4;
    const int b_tn = tid & 63;
    const int b_tk = tid >> 6;

    float acc[4][4] = {};

    for (int kt = 0; kt < K; kt += 16) {
#pragma unroll
        for (int i = 0; i < 4; ++i)
            As[a_tk][a_tm + 16 * i] =
                A[(size_t)(m0 + a_tm + 16 * i) * K + kt + a_tk];
#pragma unroll
        for (int j = 0; j < 4; ++j)
            Bs[b_tk + 4 * j][b_tn] =
                W[(size_t)(kt + b_tk + 4 * j) * N + n0 + b_tn];
        __syncthreads();

#pragma unroll
        for (int kk = 0; kk < 16; ++kk) {
            float4 av = *(const float4*)&As[kk][ty * 4];
            float4 bv = *(const float4*)&Bs[kk][tx * 4];
            float a_[4] = {av.x, av.y, av.z, av.w};
            float b_[4] = {bv.x, bv.y, bv.z, bv.w};
#pragma unroll
            for (int i = 0; i < 4; ++i)
#pragma unroll
                for (int j = 0; j < 4; ++j)
                    acc[i][j] += a_[i] * b_[j];
        }
        __syncthreads();
    }

#pragma unroll
    for (int i = 0; i < 4; ++i) {
        const int m = m0 + ty * 4 + i;
#pragma unroll
        for (int j = 0; j < 4; ++j) {
            const int n = n0 + tx * 4 + j;
            float v = acc[i][j] + bias[n];
            if constexpr (std::is_same_v<OutT, float>)
                C[(size_t)m * N + n] = v;
            else
                C[(size_t)m * N + n] = f2bf(v);
        }
    }
}

// ---------------------------------------------------------------------------
// In-place row LayerNorm over rows of length 512. One block (256 thr) per row.
// ---------------------------------------------------------------------------
__global__ __launch_bounds__(256)
void layernorm512_kernel(float* __restrict__ buf, const float* __restrict__ g,
                         const float* __restrict__ bvec) {
    const int row = blockIdx.x;
    float* p = buf + (size_t)row * L_;
    const int tid = threadIdx.x;

    float x0 = p[tid], x1 = p[tid + 256];
    float s  = x0 + x1;
    float sq = x0 * x0 + x1 * x1;

    __shared__ float red[8];
    __shared__ float stats[2];

#pragma unroll
    for (int off = 32; off; off >>= 1) {
        s  += __shfl_down(s, off);
        sq += __shfl_down(sq, off);
    }
    const int wave = tid >> 6;
    if ((tid & 63) == 0) { red[wave] = s; red[wave + 4] = sq; }
    __syncthreads();
    if (tid == 0) {
        float ts = red[0] + red[1] + red[2] + red[3];
        float tq = red[4] + red[5] + red[6] + red[7];
        float mean = ts / (float)L_;
        float var  = tq / (float)L_ - mean * mean;
        stats[0] = mean;
        stats[1] = rsqrtf(var + EPS);
    }
    __syncthreads();
    const float mean = stats[0], rstd = stats[1];
    p[tid]       = (x0 - mean) * rstd * g[tid]       + bvec[tid];
    p[tid + 256] = (x1 - mean) * rstd * g[tid + 256] + bvec[tid + 256];
}

// ---------------------------------------------------------------------------
// V transpose: vt[(b*H+h)*HD + d][s] = kv_bf[(b*S+s)*2D + D + h*HD + d]
// grid (S/64, H, B), 256 threads. 64 s x 128 d tile through LDS.
// ---------------------------------------------------------------------------
__global__ __launch_bounds__(256)
void vtrans_kernel(const u16* __restrict__ kvbf, u16* __restrict__ vt) {
    const int s0 = blockIdx.x * 64;
    const int h  = blockIdx.y, b = blockIdx.z;
    __shared__ u16 T[64][136];
    const int t = threadIdx.x;
    {
        const int sl = t >> 2, dc = (t & 3) * 32;
        const uint4* src = (const uint4*)(kvbf +
            ((size_t)(b * S_ + s0 + sl) * (2 * D_) + D_ + h * HD_ + dc));
        uint4 a0 = src[0], a1 = src[1], a2 = src[2], a3 = src[3];
        *(uint4*)&T[sl][dc]      = a0;
        *(uint4*)&T[sl][dc + 8]  = a1;
        *(uint4*)&T[sl][dc + 16] = a2;
        *(uint4*)&T[sl][dc + 24] = a3;
    }
    __syncthreads();
    {
        const int d = t >> 1, sh = (t & 1) * 32;
        union { u16 u[32]; uint4 q[4]; } buf;
#pragma unroll
        for (int i = 0; i < 32; ++i) buf.u[i] = T[sh + i][d];
        uint4* dst = (uint4*)(vt +
            ((size_t)((b * H_ + h) * HD_ + d)) * S_ + s0 + sh);
        dst[0] = buf.q[0]; dst[1] = buf.q[1];
        dst[2] = buf.q[2]; dst[3] = buf.q[3];
    }
}

// ---------------------------------------------------------------------------
// Flash attention (bf16 MFMA, online softmax).
// grid (S/128 [reversed], H, B), 256 threads (4 waves x 32 queries).
// q_bf  : [B*S, D] bf16 (head-major cols)
// kv_bf : [B*S, 2D] bf16 (K = cols [h*HD, ...))
// vt    : [(b*H+h)*HD + d][s] bf16
// out   : [B*S, D] fp32
// ---------------------------------------------------------------------------
#define KPITCH 136
#define VPITCH 40
#define PPITCH 40

__global__ __launch_bounds__(256)
void flash_attn_kernel(const u16* __restrict__ qbf, const u16* __restrict__ kvbf,
                       const u16* __restrict__ vt,
                       const unsigned char* __restrict__ mask,
                       float* __restrict__ out) {
    const int qt = (S_ / 128 - 1) - blockIdx.x;   // heavy blocks first
    const int h  = blockIdx.y, b = blockIdx.z;
    const int q0 = qt * 128;
    const int tid  = threadIdx.x;
    const int wave = tid >> 6, lane = tid & 63;
    const int l15  = lane & 15, g = lane >> 4;
    const int qw0  = q0 + wave * 32;              // this wave's 32 queries

    __shared__ __align__(16) u16 Kl[32][KPITCH];     // 8704 B
    __shared__ __align__(16) u16 Vl[HD_][VPITCH];    // 10240 B
    __shared__ __align__(16) u16 Pl[4][32][PPITCH];  // 10240 B

    // Q fragments (A-operand): qf[qg][c], q row = qw0 + qg*16 + l15,
    // d = c*32 + g*8 + j
    bf16x8 qf[2][4];
#pragma unroll
    for (int qg = 0; qg < 2; ++qg)
#pragma unroll
        for (int c = 0; c < 4; ++c)
            qf[qg][c] = *(const bf16x8*)(qbf +
                (size_t)(b * S_ + qw0 + qg * 16 + l15) * D_ +
                h * HD_ + c * 32 + g * 8);

    f32x4 o[2][8];
    float m_run[2][4], l_run[2][4];
#pragma unroll
    for (int qg = 0; qg < 2; ++qg) {
#pragma unroll
        for (int i = 0; i < 8; ++i) o[qg][i] = (f32x4)0.f;
#pragma unroll
        for (int r = 0; r < 4; ++r) { m_run[qg][r] = -INFINITY; l_run[qg][r] = 0.f; }
    }

    const int nt = q0 / 32 + 4;   // key tiles (causal: keys < q0+128)
    for (int kt = 0; kt < nt; ++kt) {
        const int k0 = kt * 32;

        // ---- stage K tile: Kl[key][d], 32 keys x 128 d ----
        {
            const int key = tid >> 3, dc = (tid & 7) * 16;
            const uint4* src = (const uint4*)(kvbf +
                ((size_t)(b * S_ + k0 + key) * (2 * D_) + h * HD_ + dc));
            uint4 a0 = src[0], a1 = src[1];
            *(uint4*)&Kl[key][dc]     = a0;
            *(uint4*)&Kl[key][dc + 8] = a1;
        }
        // ---- stage V tile: Vl[d][key], 128 d x 32 keys ----
        {
            const int d = tid >> 1, half = (tid & 1) * 16;
            const uint4* src = (const uint4*)(vt +
                ((size_t)((b * H_ + h) * HD_ + d)) * S_ + k0 + half);
            uint4 a0 = src[0], a1 = src[1];
            *(uint4*)&Vl[d][half]     = a0;
            *(uint4*)&Vl[d][half + 8] = a1;
        }
        __syncthreads();

        if (k0 <= qw0 + 31) {   // wave-uniform: any of this wave's rows need it
            // mask bytes for this lane's two key columns
            const unsigned char mv0 = mask[b * S_ + k0 + l15];
            const unsigned char mv1 = mask[b * S_ + k0 + 16 + l15];

            // K fragments (B-operand): kf[f][c] = K[k0+16f+l15][c*32+g*8+j]
            bf16x8 kf0[4], kf1[4];
#pragma unroll
            for (int c = 0; c < 4; ++c) {
                kf0[c] = *(const bf16x8*)&Kl[l15][c * 32 + g * 8];
                kf1[c] = *(const bf16x8*)&Kl[16 + l15][c * 32 + g * 8];
            }

#pragma unroll
            for (int qg = 0; qg < 2; ++qg) {
                f32x4 s0 = (f32x4)0.f, s1 = (f32x4)0.f;
#pragma unroll
                for (int c = 0; c < 4; ++c) {
                    s0 = __builtin_amdgcn_mfma_f32_16x16x32_bf16(qf[qg][c], kf0[c], s0, 0, 0, 0);
                    s1 = __builtin_amdgcn_mfma_f32_16x16x32_bf16(qf[qg][c], kf1[c], s1, 0, 0, 0);
                }
                // scale + causal/padding mask.  S element [r]:
                //   q = qw0 + qg*16 + 4g + r, k = k0 + 16f + l15
                const int qbase = qw0 + qg * 16 + 4 * g;
                const int ka = k0 + l15, kb = k0 + 16 + l15;
#pragma unroll
                for (int r = 0; r < 4; ++r) {
                    float v0 = s0[r] * SCALE, v1 = s1[r] * SCALE;
                    if (ka > qbase + r || mv0) v0 = -INFINITY;
                    if (kb > qbase + r || mv1) v1 = -INFINITY;
                    s0[r] = v0; s1[r] = v1;
                }
                // row max across 16 lanes (cols)
                float tm[4];
#pragma unroll
                for (int r = 0; r < 4; ++r) tm[r] = fmaxf(s0[r], s1[r]);
#pragma unroll
                for (int off = 1; off < 16; off <<= 1)
#pragma unroll
                    for (int r = 0; r < 4; ++r)
                        tm[r] = fmaxf(tm[r], __shfl_xor(tm[r], off));

                float alpha[4], ts[4];
#pragma unroll
                for (int r = 0; r < 4; ++r) {
                    float nm = fmaxf(m_run[qg][r], tm[r]);
                    alpha[r] = __expf(m_run[qg][r] - nm);
                    m_run[qg][r] = nm;
                    s0[r] = __expf(s0[r] - nm);
                    s1[r] = __expf(s1[r] - nm);
                    ts[r] = s0[r] + s1[r];
                }
#pragma unroll
                for (int off = 1; off < 16; off <<= 1)
#pragma unroll
                    for (int r = 0; r < 4; ++r)
                        ts[r] += __shfl_xor(ts[r], off);
#pragma unroll
                for (int r = 0; r < 4; ++r)
                    l_run[qg][r] = l_run[qg][r] * alpha[r] + ts[r];

                // rescale O
                f32x4 av; av[0]=alpha[0]; av[1]=alpha[1]; av[2]=alpha[2]; av[3]=alpha[3];
#pragma unroll
                for (int i = 0; i < 8; ++i) o[qg][i] *= av;

                // P -> LDS (C-layout scatter, bf16)
#pragma unroll
                for (int r = 0; r < 4; ++r) {
                    Pl[wave][qg * 16 + 4 * g + r][l15]      = f2bf(s0[r]);
                    Pl[wave][qg * 16 + 4 * g + r][16 + l15] = f2bf(s1[r]);
                }
            }

            // PV: read P in A-layout, V fragments in B-layout
            bf16x8 pf0 = *(const bf16x8*)&Pl[wave][l15][g * 8];
            bf16x8 pf1 = *(const bf16x8*)&Pl[wave][16 + l15][g * 8];
#pragma unroll
            for (int i = 0; i < 8; ++i) {
                bf16x8 vf = *(const bf16x8*)&Vl[16 * i + l15][g * 8];
                o[0][i] = __builtin_amdgcn_mfma_f32_16x16x32_bf16(pf0, vf, o[0][i], 0, 0, 0);
                o[1][i] = __builtin_amdgcn_mfma_f32_16x16x32_bf16(pf1, vf, o[1][i], 0, 0, 0);
            }
        }
        __syncthreads();
    }

    // epilogue: normalize, write fp32
#pragma unroll
    for (int qg = 0; qg < 2; ++qg) {
        f32x4 inv;
#pragma unroll
        for (int r = 0; r < 4; ++r) inv[r] = 1.0f / l_run[qg][r];
#pragma unroll
        for (int i = 0; i < 8; ++i) {
            f32x4 res = o[qg][i] * inv;
#pragma unroll
            for (int r = 0; r < 4; ++r)
                out[(size_t)(b * S_ + qw0 + qg * 16 + 4 * g + r) * D_ +
                    h * HD_ + 16 * i + l15] = res[r];
        }
    }
}

// ---------------------------------------------------------------------------
extern "C" void kernel_launch(void* const* d_in, const int* in_sizes, int n_in,
                              void* d_out, int out_size, void* d_ws, size_t ws_size,
                              hipStream_t stream) {
    const float* x        = (const float*)d_in[0];
    const unsigned char* mask = (const unsigned char*)d_in[1];
    const float* wq_down  = (const float*)d_in[2];
    const float* bq_down  = (const float*)d_in[3];
    const float* gq_ln    = (const float*)d_in[4];
    const float* bq_ln    = (const float*)d_in[5];
    const float* wq_up    = (const float*)d_in[6];
    const float* bq_up    = (const float*)d_in[7];
    const float* wkv_down = (const float*)d_in[8];
    const float* bkv_down = (const float*)d_in[9];
    const float* gkv_ln   = (const float*)d_in[10];
    const float* bkv_ln   = (const float*)d_in[11];
    const float* wkv_up   = (const float*)d_in[12];
    const float* bkv_up   = (const float*)d_in[13];
    const float* w_out    = (const float*)d_in[14];
    const float* b_out    = (const float*)d_in[15];
    float* out = (float*)d_out;

    // Workspace layout (float offsets):
    //   [0,        2M)  q_lat   (dead after q-up)   \ overlaid by vt (4M floats
    //   [2M,       4M)  kv_lat  (dead after kv-up)  /  = 8.4M u16) afterwards
    //   [4M,      12M)  attn fp32 [4096 x 2048]
    //   [12M,     16M)  q_bf  u16 [4096 x 2048]
    //   [16M,     24M)  kv_bf u16 [4096 x 4096]
    float* ws     = (float*)d_ws;
    float* q_lat  = ws;
    float* kv_lat = ws + (size_t)2097152;
    u16*   vt     = (u16*)ws;
    float* attn   = ws + (size_t)4194304;
    u16*   q_bf   = (u16*)(ws + (size_t)12582912);
    u16*   kv_bf  = (u16*)(ws + (size_t)16777216);

    const int M = B_ * S_;  // 4096
    dim3 blk(256);

    // Q path
    gemm_bias_kernel<float><<<dim3(L_ / 64, M / 64), blk, 0, stream>>>(
        x, wq_down, bq_down, q_lat, M, L_, D_);
    layernorm512_kernel<<<M, blk, 0, stream>>>(q_lat, gq_ln, bq_ln);
    gemm_bias_kernel<u16><<<dim3(D_ / 64, M / 64), blk, 0, stream>>>(
        q_lat, wq_up, bq_up, q_bf, M, D_, L_);

    // KV path
    gemm_bias_kernel<float><<<dim3(L_ / 64, M / 64), blk, 0, stream>>>(
        x, wkv_down, bkv_down, kv_lat, M, L_, D_);
    layernorm512_kernel<<<M, blk, 0, stream>>>(kv_lat, gkv_ln, bkv_ln);
    gemm_bias_kernel<u16><<<dim3((2 * D_) / 64, M / 64), blk, 0, stream>>>(
        kv_lat, wkv_up, bkv_up, kv_bf, M, 2 * D_, L_);

    // V transpose (reads kv_bf, writes vt over the dead lat buffers)
    vtrans_kernel<<<dim3(S_ / 64, H_, B_), blk, 0, stream>>>(kv_bf, vt);

    // Flash attention
    flash_attn_kernel<<<dim3(S_ / 128, H_, B_), blk, 0, stream>>>(
        q_bf, kv_bf, vt, mask, attn);

    // Output projection (fp32)
    gemm_bias_kernel<float><<<dim3(D_ / 64, M / 64), blk, 0, stream>>>(
        attn, w_out, b_out, out, M, D_, D_);
}

// Round 3
// 658.609 us; speedup vs baseline: 10.0612x; 2.3385x over previous
//
#include <hip/hip_runtime.h>
#include <math.h>
#include <type_traits>

typedef unsigned short u16;
typedef __attribute__((ext_vector_type(8))) short bf16x8;
typedef __attribute__((ext_vector_type(4))) float f32x4;

// Problem constants (fixed by the reference)
#define B_  2
#define S_  2048
#define D_  2048
#define H_  16
#define HD_ 128
#define L_  512
constexpr float EPS   = 1e-5f;
constexpr float SCALE = 0.08838834764831845f; // 1/sqrt(128)

__device__ __forceinline__ u16 f2bf(float x) {
    unsigned u = __float_as_uint(x);
    u += 0x7fffu + ((u >> 16) & 1u);   // round-to-nearest-even
    return (u16)(u >> 16);
}
__device__ __forceinline__ float bf2f(u16 v) {
    return __uint_as_float(((unsigned)v) << 16);
}

// async global->LDS, 16 B per lane; LDS dest = lptr + lane*16 (wave-uniform base)
__device__ __forceinline__ void gl_lds16(const u16* g, u16* l) {
    __builtin_amdgcn_global_load_lds(
        (const __attribute__((address_space(1))) unsigned int*)g,
        (__attribute__((address_space(3))) unsigned int*)l, 16, 0, 0);
}

// ---------------------------------------------------------------------------
// bf16 MFMA GEMM (m97 structure): C[M,N] = A[M,K] @ Bt[N,K]^T + bias[N]
// A, Bt bf16 row-major (k contiguous). 128x128 block tile, BK=32, 256 thr,
// 4 waves each computing 64x64 via 4x4 mfma_f32_16x16x32_bf16.
// LDS tiles [128 rows][32 k] with XOR chunk swizzle p = c ^ ((r>>1)&3)
// (8-bf16 chunks) -> global_load_lds staging stays lane-contiguous while
// ds_read_b128 fragment reads are 2-way/bank (free).
// Requires M%128==0, N%128==0, K%32==0.
// ---------------------------------------------------------------------------
template <typename OutT>
__global__ __launch_bounds__(256)
void gemm_mfma_kernel(const u16* __restrict__ A, const u16* __restrict__ Bt,
                      const float* __restrict__ bias, OutT* __restrict__ C,
                      int M, int N, int K) {
    __shared__ __align__(16) u16 As[128 * 32];
    __shared__ __align__(16) u16 Bs[128 * 32];

    const int tid  = threadIdx.x;
    const int wave = tid >> 6, lane = tid & 63;
    const int l15  = lane & 15, g = lane >> 4;
    const int wm   = wave >> 1, wn = wave & 1;
    const int m0   = blockIdx.y * 128, n0 = blockIdx.x * 128;

    // staging lane mapping: 16 rows / instruction, 4 chunk-slots / row
    const int sr = lane >> 2;       // row within 16-row group
    const int sc = lane & 3;        // chunk slot (position p in LDS)

    const int swz = (l15 >> 1) & 3; // read-side swizzle key (uniform over i,g)

    f32x4 acc[4][4];
#pragma unroll
    for (int i = 0; i < 4; ++i)
#pragma unroll
        for (int j = 0; j < 4; ++j) acc[i][j] = (f32x4)0.f;

    for (int k0 = 0; k0 < K; k0 += 32) {
        // ---- stage: each wave issues 2 A + 2 B global_load_lds (16 rows ea.)
#pragma unroll
        for (int t = 0; t < 2; ++t) {
            const int r  = wave * 32 + t * 16 + sr;       // row in tile
            const int c  = sc ^ ((r >> 1) & 3);           // global chunk
            gl_lds16(A  + (size_t)(m0 + r) * K + k0 + c * 8,
                     &As[(wave * 32 + t * 16) * 32]);
            gl_lds16(Bt + (size_t)(n0 + r) * K + k0 + c * 8,
                     &Bs[(wave * 32 + t * 16) * 32]);
        }
        __syncthreads();   // drains vmcnt (staging visible)

        bf16x8 af[4], bfr[4];
#pragma unroll
        for (int i = 0; i < 4; ++i) {
            const int ra = wm * 64 + i * 16 + l15;
            af[i]  = *(const bf16x8*)&As[ra * 32 + (g ^ swz) * 8];
            const int rb = wn * 64 + i * 16 + l15;
            bfr[i] = *(const bf16x8*)&Bs[rb * 32 + (g ^ swz) * 8];
        }
#pragma unroll
        for (int i = 0; i < 4; ++i)
#pragma unroll
            for (int j = 0; j < 4; ++j)
                acc[i][j] = __builtin_amdgcn_mfma_f32_16x16x32_bf16(
                    af[i], bfr[j], acc[i][j], 0, 0, 0);
        __syncthreads();   // compute done before next overwrite
    }

    // epilogue: C element (m = .. + g*4 + r, n = .. + l15)
#pragma unroll
    for (int j = 0; j < 4; ++j) {
        const int n  = n0 + wn * 64 + j * 16 + l15;
        const float bv = bias[n];
#pragma unroll
        for (int i = 0; i < 4; ++i) {
            const int mb = m0 + wm * 64 + i * 16 + g * 4;
#pragma unroll
            for (int r = 0; r < 4; ++r) {
                float v = acc[i][j][r] + bv;
                if constexpr (std::is_same_v<OutT, float>)
                    C[(size_t)(mb + r) * N + n] = v;
                else
                    C[(size_t)(mb + r) * N + n] = f2bf(v);
            }
        }
    }
}

// ---------------------------------------------------------------------------
// fp32 -> bf16 cast (x), 4 elements/thread
// ---------------------------------------------------------------------------
__global__ __launch_bounds__(256)
void cast_bf16_kernel(const float* __restrict__ src, u16* __restrict__ dst,
                      int n4) {
    const int i = blockIdx.x * 256 + threadIdx.x;
    if (i < n4) {
        float4 f = ((const float4*)src)[i];
        ushort4 o;
        o.x = f2bf(f.x); o.y = f2bf(f.y); o.z = f2bf(f.z); o.w = f2bf(f.w);
        ((ushort4*)dst)[i] = o;
    }
}

// ---------------------------------------------------------------------------
// fp32 W[K,N] -> bf16 Wt[N,K].  grid (N/64, K/64), 256 thr, 64x64 LDS tile.
// ---------------------------------------------------------------------------
__global__ __launch_bounds__(256)
void cast_transpose_kernel(const float* __restrict__ W, u16* __restrict__ Wt,
                           int K, int N) {
    __shared__ u16 T[64][72];
    const int n0 = blockIdx.x * 64, k0 = blockIdx.y * 64;
    const int t  = threadIdx.x;
    {
        const int kr = t >> 2, nc = (t & 3) * 16;
#pragma unroll
        for (int v = 0; v < 4; ++v) {
            float4 f = *(const float4*)&W[(size_t)(k0 + kr) * N + n0 + nc + v * 4];
            T[nc + v * 4 + 0][kr] = f2bf(f.x);
            T[nc + v * 4 + 1][kr] = f2bf(f.y);
            T[nc + v * 4 + 2][kr] = f2bf(f.z);
            T[nc + v * 4 + 3][kr] = f2bf(f.w);
        }
    }
    __syncthreads();
    {
        const int nr = t >> 2, kc = (t & 3) * 16;
        union { u16 u[16]; uint4 q[2]; } o;
#pragma unroll
        for (int i = 0; i < 16; ++i) o.u[i] = T[nr][kc + i];
        uint4* dst = (uint4*)&Wt[(size_t)(n0 + nr) * K + k0 + kc];
        dst[0] = o.q[0]; dst[1] = o.q[1];
    }
}

// ---------------------------------------------------------------------------
// In-place bf16 row LayerNorm, rows of 512. One block (256 thr) per row.
// ---------------------------------------------------------------------------
__global__ __launch_bounds__(256)
void layernorm512_bf16_kernel(u16* __restrict__ buf, const float* __restrict__ g,
                              const float* __restrict__ bvec) {
    const int row = blockIdx.x;
    u16* p = buf + (size_t)row * L_;
    const int tid = threadIdx.x;

    float x0 = bf2f(p[tid]), x1 = bf2f(p[tid + 256]);
    float s  = x0 + x1;
    float sq = x0 * x0 + x1 * x1;

    __shared__ float red[8];
    __shared__ float stats[2];

#pragma unroll
    for (int off = 32; off; off >>= 1) {
        s  += __shfl_down(s, off);
        sq += __shfl_down(sq, off);
    }
    const int wave = tid >> 6;
    if ((tid & 63) == 0) { red[wave] = s; red[wave + 4] = sq; }
    __syncthreads();
    if (tid == 0) {
        float ts = red[0] + red[1] + red[2] + red[3];
        float tq = red[4] + red[5] + red[6] + red[7];
        float mean = ts / (float)L_;
        float var  = tq / (float)L_ - mean * mean;
        stats[0] = mean;
        stats[1] = rsqrtf(var + EPS);
    }
    __syncthreads();
    const float mean = stats[0], rstd = stats[1];
    p[tid]       = f2bf((x0 - mean) * rstd * g[tid]       + bvec[tid]);
    p[tid + 256] = f2bf((x1 - mean) * rstd * g[tid + 256] + bvec[tid + 256]);
}

// ---------------------------------------------------------------------------
// V transpose: vt[(b*H+h)*HD + d][s] = kv_bf[(b*S+s)*2D + D + h*HD + d]
// ---------------------------------------------------------------------------
__global__ __launch_bounds__(256)
void vtrans_kernel(const u16* __restrict__ kvbf, u16* __restrict__ vt) {
    const int s0 = blockIdx.x * 64;
    const int h  = blockIdx.y, b = blockIdx.z;
    __shared__ u16 T[64][136];
    const int t = threadIdx.x;
    {
        const int sl = t >> 2, dc = (t & 3) * 32;
        const uint4* src = (const uint4*)(kvbf +
            ((size_t)(b * S_ + s0 + sl) * (2 * D_) + D_ + h * HD_ + dc));
        uint4 a0 = src[0], a1 = src[1], a2 = src[2], a3 = src[3];
        *(uint4*)&T[sl][dc]      = a0;
        *(uint4*)&T[sl][dc + 8]  = a1;
        *(uint4*)&T[sl][dc + 16] = a2;
        *(uint4*)&T[sl][dc + 24] = a3;
    }
    __syncthreads();
    {
        const int d = t >> 1, sh = (t & 1) * 32;
        union { u16 u[32]; uint4 q[4]; } buf;
#pragma unroll
        for (int i = 0; i < 32; ++i) buf.u[i] = T[sh + i][d];
        uint4* dst = (uint4*)(vt +
            ((size_t)((b * H_ + h) * HD_ + d)) * S_ + s0 + sh);
        dst[0] = buf.q[0]; dst[1] = buf.q[1];
        dst[2] = buf.q[2]; dst[3] = buf.q[3];
    }
}

// ---------------------------------------------------------------------------
// Flash attention (bf16 MFMA, online softmax). out is bf16 now.
// grid (S/128 [reversed], H, B), 256 threads (4 waves x 32 queries).
// ---------------------------------------------------------------------------
#define KPITCH 136
#define VPITCH 40
#define PPITCH 40

__global__ __launch_bounds__(256)
void flash_attn_kernel(const u16* __restrict__ qbf, const u16* __restrict__ kvbf,
                       const u16* __restrict__ vt,
                       const unsigned char* __restrict__ mask,
                       u16* __restrict__ out) {
    const int qt = (S_ / 128 - 1) - blockIdx.x;   // heavy blocks first
    const int h  = blockIdx.y, b = blockIdx.z;
    const int q0 = qt * 128;
    const int tid  = threadIdx.x;
    const int wave = tid >> 6, lane = tid & 63;
    const int l15  = lane & 15, g = lane >> 4;
    const int qw0  = q0 + wave * 32;

    __shared__ __align__(16) u16 Kl[32][KPITCH];
    __shared__ __align__(16) u16 Vl[HD_][VPITCH];
    __shared__ __align__(16) u16 Pl[4][32][PPITCH];

    bf16x8 qf[2][4];
#pragma unroll
    for (int qg = 0; qg < 2; ++qg)
#pragma unroll
        for (int c = 0; c < 4; ++c)
            qf[qg][c] = *(const bf16x8*)(qbf +
                (size_t)(b * S_ + qw0 + qg * 16 + l15) * D_ +
                h * HD_ + c * 32 + g * 8);

    f32x4 o[2][8];
    float m_run[2][4], l_run[2][4];
#pragma unroll
    for (int qg = 0; qg < 2; ++qg) {
#pragma unroll
        for (int i = 0; i < 8; ++i) o[qg][i] = (f32x4)0.f;
#pragma unroll
        for (int r = 0; r < 4; ++r) { m_run[qg][r] = -INFINITY; l_run[qg][r] = 0.f; }
    }

    const int nt = q0 / 32 + 4;
    for (int kt = 0; kt < nt; ++kt) {
        const int k0 = kt * 32;
        {
            const int key = tid >> 3, dc = (tid & 7) * 16;
            const uint4* src = (const uint4*)(kvbf +
                ((size_t)(b * S_ + k0 + key) * (2 * D_) + h * HD_ + dc));
            uint4 a0 = src[0], a1 = src[1];
            *(uint4*)&Kl[key][dc]     = a0;
            *(uint4*)&Kl[key][dc + 8] = a1;
        }
        {
            const int d = tid >> 1, half = (tid & 1) * 16;
            const uint4* src = (const uint4*)(vt +
                ((size_t)((b * H_ + h) * HD_ + d)) * S_ + k0 + half);
            uint4 a0 = src[0], a1 = src[1];
            *(uint4*)&Vl[d][half]     = a0;
            *(uint4*)&Vl[d][half + 8] = a1;
        }
        __syncthreads();

        if (k0 <= qw0 + 31) {
            const unsigned char mv0 = mask[b * S_ + k0 + l15];
            const unsigned char mv1 = mask[b * S_ + k0 + 16 + l15];

            bf16x8 kf0[4], kf1[4];
#pragma unroll
            for (int c = 0; c < 4; ++c) {
                kf0[c] = *(const bf16x8*)&Kl[l15][c * 32 + g * 8];
                kf1[c] = *(const bf16x8*)&Kl[16 + l15][c * 32 + g * 8];
            }

#pragma unroll
            for (int qg = 0; qg < 2; ++qg) {
                f32x4 s0 = (f32x4)0.f, s1 = (f32x4)0.f;
#pragma unroll
                for (int c = 0; c < 4; ++c) {
                    s0 = __builtin_amdgcn_mfma_f32_16x16x32_bf16(qf[qg][c], kf0[c], s0, 0, 0, 0);
                    s1 = __builtin_amdgcn_mfma_f32_16x16x32_bf16(qf[qg][c], kf1[c], s1, 0, 0, 0);
                }
                const int qbase = qw0 + qg * 16 + 4 * g;
                const int ka = k0 + l15, kb = k0 + 16 + l15;
#pragma unroll
                for (int r = 0; r < 4; ++r) {
                    float v0 = s0[r] * SCALE, v1 = s1[r] * SCALE;
                    if (ka > qbase + r || mv0) v0 = -INFINITY;
                    if (kb > qbase + r || mv1) v1 = -INFINITY;
                    s0[r] = v0; s1[r] = v1;
                }
                float tm[4];
#pragma unroll
                for (int r = 0; r < 4; ++r) tm[r] = fmaxf(s0[r], s1[r]);
#pragma unroll
                for (int off = 1; off < 16; off <<= 1)
#pragma unroll
                    for (int r = 0; r < 4; ++r)
                        tm[r] = fmaxf(tm[r], __shfl_xor(tm[r], off));

                float alpha[4], ts[4];
#pragma unroll
                for (int r = 0; r < 4; ++r) {
                    float nm = fmaxf(m_run[qg][r], tm[r]);
                    alpha[r] = __expf(m_run[qg][r] - nm);
                    m_run[qg][r] = nm;
                    s0[r] = __expf(s0[r] - nm);
                    s1[r] = __expf(s1[r] - nm);
                    ts[r] = s0[r] + s1[r];
                }
#pragma unroll
                for (int off = 1; off < 16; off <<= 1)
#pragma unroll
                    for (int r = 0; r < 4; ++r)
                        ts[r] += __shfl_xor(ts[r], off);
#pragma unroll
                for (int r = 0; r < 4; ++r)
                    l_run[qg][r] = l_run[qg][r] * alpha[r] + ts[r];

                f32x4 av; av[0]=alpha[0]; av[1]=alpha[1]; av[2]=alpha[2]; av[3]=alpha[3];
#pragma unroll
                for (int i = 0; i < 8; ++i) o[qg][i] *= av;

#pragma unroll
                for (int r = 0; r < 4; ++r) {
                    Pl[wave][qg * 16 + 4 * g + r][l15]      = f2bf(s0[r]);
                    Pl[wave][qg * 16 + 4 * g + r][16 + l15] = f2bf(s1[r]);
                }
            }

            bf16x8 pf0 = *(const bf16x8*)&Pl[wave][l15][g * 8];
            bf16x8 pf1 = *(const bf16x8*)&Pl[wave][16 + l15][g * 8];
#pragma unroll
            for (int i = 0; i < 8; ++i) {
                bf16x8 vf = *(const bf16x8*)&Vl[16 * i + l15][g * 8];
                o[0][i] = __builtin_amdgcn_mfma_f32_16x16x32_bf16(pf0, vf, o[0][i], 0, 0, 0);
                o[1][i] = __builtin_amdgcn_mfma_f32_16x16x32_bf16(pf1, vf, o[1][i], 0, 0, 0);
            }
        }
        __syncthreads();
    }

#pragma unroll
    for (int qg = 0; qg < 2; ++qg) {
        f32x4 inv;
#pragma unroll
        for (int r = 0; r < 4; ++r) inv[r] = 1.0f / l_run[qg][r];
#pragma unroll
        for (int i = 0; i < 8; ++i) {
            f32x4 res = o[qg][i] * inv;
#pragma unroll
            for (int r = 0; r < 4; ++r)
                out[(size_t)(b * S_ + qw0 + qg * 16 + 4 * g + r) * D_ +
                    h * HD_ + 16 * i + l15] = f2bf(res[r]);
        }
    }
}

// ---------------------------------------------------------------------------
extern "C" void kernel_launch(void* const* d_in, const int* in_sizes, int n_in,
                              void* d_out, int out_size, void* d_ws, size_t ws_size,
                              hipStream_t stream) {
    const float* x        = (const float*)d_in[0];
    const unsigned char* mask = (const unsigned char*)d_in[1];
    const float* wq_down  = (const float*)d_in[2];
    const float* bq_down  = (const float*)d_in[3];
    const float* gq_ln    = (const float*)d_in[4];
    const float* bq_ln    = (const float*)d_in[5];
    const float* wq_up    = (const float*)d_in[6];
    const float* bq_up    = (const float*)d_in[7];
    const float* wkv_down = (const float*)d_in[8];
    const float* bkv_down = (const float*)d_in[9];
    const float* gkv_ln   = (const float*)d_in[10];
    const float* bkv_ln   = (const float*)d_in[11];
    const float* wkv_up   = (const float*)d_in[12];
    const float* bkv_up   = (const float*)d_in[13];
    const float* w_out    = (const float*)d_in[14];
    const float* b_out    = (const float*)d_in[15];
    float* out = (float*)d_out;

    // Workspace layout (byte offsets, MB). Total 90 MB (<96 MB proven in R1).
    //   [ 0,16)  x_bf              -> vt after q path done
    //   [16,20)  kv_lat_bf  \
    //   [20,24)  q_lat_bf    \
    //   [24,26)  wkvd_t       >    -> attn_bf [16,32) after both up-projs
    //   [26,28)  wqd_t       /
    //   [28,32)  wkvu_t     /
    //   [32,34)  wqu_t
    //   [34,42)  wout_t  (live till end)
    //   [42,58)  q_bf
    //   [58,90)  kv_bf
    char* ws = (char*)d_ws;
    u16* x_bf      = (u16*)(ws);
    u16* vt        = (u16*)(ws);
    u16* kv_lat_bf = (u16*)(ws + (16u << 20));
    u16* attn_bf   = (u16*)(ws + (16u << 20));
    u16* q_lat_bf  = (u16*)(ws + (20u << 20));
    u16* wkvd_t    = (u16*)(ws + (24u << 20));
    u16* wqd_t     = (u16*)(ws + (26u << 20));
    u16* wkvu_t    = (u16*)(ws + (28u << 20));
    u16* wqu_t     = (u16*)(ws + (32u << 20));
    u16* wout_t    = (u16*)(ws + (34u << 20));
    u16* q_bf      = (u16*)(ws + (42u << 20));
    u16* kv_bf     = (u16*)(ws + (58u << 20));

    const int M = B_ * S_;  // 4096
    dim3 blk(256);

    // casts / transposes
    cast_bf16_kernel<<<(M * D_ / 4 + 255) / 256, blk, 0, stream>>>(x, x_bf, M * D_ / 4);
    cast_transpose_kernel<<<dim3(L_ / 64, D_ / 64), blk, 0, stream>>>(wq_down,  wqd_t,  D_, L_);
    cast_transpose_kernel<<<dim3(D_ / 64, L_ / 64), blk, 0, stream>>>(wq_up,    wqu_t,  L_, D_);
    cast_transpose_kernel<<<dim3(L_ / 64, D_ / 64), blk, 0, stream>>>(wkv_down, wkvd_t, D_, L_);
    cast_transpose_kernel<<<dim3(2 * D_ / 64, L_ / 64), blk, 0, stream>>>(wkv_up, wkvu_t, L_, 2 * D_);
    cast_transpose_kernel<<<dim3(D_ / 64, D_ / 64), blk, 0, stream>>>(w_out,    wout_t, D_, D_);

    // KV path
    gemm_mfma_kernel<u16><<<dim3(L_ / 128, M / 128), blk, 0, stream>>>(
        x_bf, wkvd_t, bkv_down, kv_lat_bf, M, L_, D_);
    layernorm512_bf16_kernel<<<M, blk, 0, stream>>>(kv_lat_bf, gkv_ln, bkv_ln);
    gemm_mfma_kernel<u16><<<dim3(2 * D_ / 128, M / 128), blk, 0, stream>>>(
        kv_lat_bf, wkvu_t, bkv_up, kv_bf, M, 2 * D_, L_);

    // Q path
    gemm_mfma_kernel<u16><<<dim3(L_ / 128, M / 128), blk, 0, stream>>>(
        x_bf, wqd_t, bq_down, q_lat_bf, M, L_, D_);
    layernorm512_bf16_kernel<<<M, blk, 0, stream>>>(q_lat_bf, gq_ln, bq_ln);
    gemm_mfma_kernel<u16><<<dim3(D_ / 128, M / 128), blk, 0, stream>>>(
        q_lat_bf, wqu_t, bq_up, q_bf, M, D_, L_);

    // V transpose (x_bf dead now; vt overlays it)
    vtrans_kernel<<<dim3(S_ / 64, H_, B_), blk, 0, stream>>>(kv_bf, vt);

    // Flash attention -> bf16 attn
    flash_attn_kernel<<<dim3(S_ / 128, H_, B_), blk, 0, stream>>>(
        q_bf, kv_bf, vt, mask, attn_bf);

    // Output projection (fp32 out)
    gemm_mfma_kernel<float><<<dim3(D_ / 128, M / 128), blk, 0, stream>>>(
        attn_bf, wout_t, b_out, out, M, D_, D_);
}

// Round 4
// 648.336 us; speedup vs baseline: 10.2206x; 1.0158x over previous
//
#include <hip/hip_runtime.h>
#include <math.h>
#include <type_traits>

typedef unsigned short u16;
typedef __attribute__((ext_vector_type(8))) short bf16x8;
typedef __attribute__((ext_vector_type(4))) float f32x4;

// Problem constants (fixed by the reference)
#define B_  2
#define S_  2048
#define D_  2048
#define H_  16
#define HD_ 128
#define L_  512
constexpr float EPS   = 1e-5f;
constexpr float SCALE = 0.08838834764831845f; // 1/sqrt(128)

__device__ __forceinline__ u16 f2bf(float x) {
    unsigned u = __float_as_uint(x);
    u += 0x7fffu + ((u >> 16) & 1u);   // round-to-nearest-even
    return (u16)(u >> 16);
}
__device__ __forceinline__ float bf2f(u16 v) {
    return __uint_as_float(((unsigned)v) << 16);
}

// async global->LDS, 16 B per lane; LDS dest = lptr + lane*16 (wave-uniform base)
__device__ __forceinline__ void gl_lds16(const u16* g, u16* l) {
    __builtin_amdgcn_global_load_lds(
        (const __attribute__((address_space(1))) unsigned int*)g,
        (__attribute__((address_space(3))) unsigned int*)l, 16, 0, 0);
}

// ---------------------------------------------------------------------------
// bf16 MFMA GEMM (m97 structure): C[M,N] = A[M,K] @ Bt[N,K]^T + bias[N]
// 128x128 tile, BK=32, 256 thr, 4 waves x (64x64 via 4x4 mfma 16x16x32).
// ---------------------------------------------------------------------------
template <typename OutT>
__global__ __launch_bounds__(256)
void gemm_mfma_kernel(const u16* __restrict__ A, const u16* __restrict__ Bt,
                      const float* __restrict__ bias, OutT* __restrict__ C,
                      int M, int N, int K) {
    __shared__ __align__(16) u16 As[128 * 32];
    __shared__ __align__(16) u16 Bs[128 * 32];

    const int tid  = threadIdx.x;
    const int wave = tid >> 6, lane = tid & 63;
    const int l15  = lane & 15, g = lane >> 4;
    const int wm   = wave >> 1, wn = wave & 1;
    const int m0   = blockIdx.y * 128, n0 = blockIdx.x * 128;

    const int sr = lane >> 2;       // staging row within 16-row group
    const int sc = lane & 3;        // chunk slot
    const int swz = (l15 >> 1) & 3; // read-side swizzle key

    f32x4 acc[4][4];
#pragma unroll
    for (int i = 0; i < 4; ++i)
#pragma unroll
        for (int j = 0; j < 4; ++j) acc[i][j] = (f32x4)0.f;

    for (int k0 = 0; k0 < K; k0 += 32) {
#pragma unroll
        for (int t = 0; t < 2; ++t) {
            const int r  = wave * 32 + t * 16 + sr;
            const int c  = sc ^ ((r >> 1) & 3);
            gl_lds16(A  + (size_t)(m0 + r) * K + k0 + c * 8,
                     &As[(wave * 32 + t * 16) * 32]);
            gl_lds16(Bt + (size_t)(n0 + r) * K + k0 + c * 8,
                     &Bs[(wave * 32 + t * 16) * 32]);
        }
        __syncthreads();

        bf16x8 af[4], bfr[4];
#pragma unroll
        for (int i = 0; i < 4; ++i) {
            const int ra = wm * 64 + i * 16 + l15;
            af[i]  = *(const bf16x8*)&As[ra * 32 + (g ^ swz) * 8];
            const int rb = wn * 64 + i * 16 + l15;
            bfr[i] = *(const bf16x8*)&Bs[rb * 32 + (g ^ swz) * 8];
        }
#pragma unroll
        for (int i = 0; i < 4; ++i)
#pragma unroll
            for (int j = 0; j < 4; ++j)
                acc[i][j] = __builtin_amdgcn_mfma_f32_16x16x32_bf16(
                    af[i], bfr[j], acc[i][j], 0, 0, 0);
        __syncthreads();
    }

#pragma unroll
    for (int j = 0; j < 4; ++j) {
        const int n  = n0 + wn * 64 + j * 16 + l15;
        const float bv = bias[n];
#pragma unroll
        for (int i = 0; i < 4; ++i) {
            const int mb = m0 + wm * 64 + i * 16 + g * 4;
#pragma unroll
            for (int r = 0; r < 4; ++r) {
                float v = acc[i][j][r] + bv;
                if constexpr (std::is_same_v<OutT, float>)
                    C[(size_t)(mb + r) * N + n] = v;
                else
                    C[(size_t)(mb + r) * N + n] = f2bf(v);
            }
        }
    }
}

// ---------------------------------------------------------------------------
// fp32 -> bf16 cast
// ---------------------------------------------------------------------------
__global__ __launch_bounds__(256)
void cast_bf16_kernel(const float* __restrict__ src, u16* __restrict__ dst,
                      int n4) {
    const int i = blockIdx.x * 256 + threadIdx.x;
    if (i < n4) {
        float4 f = ((const float4*)src)[i];
        ushort4 o;
        o.x = f2bf(f.x); o.y = f2bf(f.y); o.z = f2bf(f.z); o.w = f2bf(f.w);
        ((ushort4*)dst)[i] = o;
    }
}

// ---------------------------------------------------------------------------
// fp32 W[K,N] -> bf16 Wt[N,K]
// ---------------------------------------------------------------------------
__global__ __launch_bounds__(256)
void cast_transpose_kernel(const float* __restrict__ W, u16* __restrict__ Wt,
                           int K, int N) {
    __shared__ u16 T[64][72];
    const int n0 = blockIdx.x * 64, k0 = blockIdx.y * 64;
    const int t  = threadIdx.x;
    {
        const int kr = t >> 2, nc = (t & 3) * 16;
#pragma unroll
        for (int v = 0; v < 4; ++v) {
            float4 f = *(const float4*)&W[(size_t)(k0 + kr) * N + n0 + nc + v * 4];
            T[nc + v * 4 + 0][kr] = f2bf(f.x);
            T[nc + v * 4 + 1][kr] = f2bf(f.y);
            T[nc + v * 4 + 2][kr] = f2bf(f.z);
            T[nc + v * 4 + 3][kr] = f2bf(f.w);
        }
    }
    __syncthreads();
    {
        const int nr = t >> 2, kc = (t & 3) * 16;
        union { u16 u[16]; uint4 q[2]; } o;
#pragma unroll
        for (int i = 0; i < 16; ++i) o.u[i] = T[nr][kc + i];
        uint4* dst = (uint4*)&Wt[(size_t)(n0 + nr) * K + k0 + kc];
        dst[0] = o.q[0]; dst[1] = o.q[1];
    }
}

// ---------------------------------------------------------------------------
// In-place bf16 row LayerNorm, rows of 512
// ---------------------------------------------------------------------------
__global__ __launch_bounds__(256)
void layernorm512_bf16_kernel(u16* __restrict__ buf, const float* __restrict__ g,
                              const float* __restrict__ bvec) {
    const int row = blockIdx.x;
    u16* p = buf + (size_t)row * L_;
    const int tid = threadIdx.x;

    float x0 = bf2f(p[tid]), x1 = bf2f(p[tid + 256]);
    float s  = x0 + x1;
    float sq = x0 * x0 + x1 * x1;

    __shared__ float red[8];
    __shared__ float stats[2];

#pragma unroll
    for (int off = 32; off; off >>= 1) {
        s  += __shfl_down(s, off);
        sq += __shfl_down(sq, off);
    }
    const int wave = tid >> 6;
    if ((tid & 63) == 0) { red[wave] = s; red[wave + 4] = sq; }
    __syncthreads();
    if (tid == 0) {
        float ts = red[0] + red[1] + red[2] + red[3];
        float tq = red[4] + red[5] + red[6] + red[7];
        float mean = ts / (float)L_;
        float var  = tq / (float)L_ - mean * mean;
        stats[0] = mean;
        stats[1] = rsqrtf(var + EPS);
    }
    __syncthreads();
    const float mean = stats[0], rstd = stats[1];
    p[tid]       = f2bf((x0 - mean) * rstd * g[tid]       + bvec[tid]);
    p[tid + 256] = f2bf((x1 - mean) * rstd * g[tid + 256] + bvec[tid + 256]);
}

// ---------------------------------------------------------------------------
// V transpose: vt[(b*H+h)*HD + d][s] = kv_bf[(b*S+s)*2D + D + h*HD + d]
// ---------------------------------------------------------------------------
__global__ __launch_bounds__(256)
void vtrans_kernel(const u16* __restrict__ kvbf, u16* __restrict__ vt) {
    const int s0 = blockIdx.x * 64;
    const int h  = blockIdx.y, b = blockIdx.z;
    __shared__ u16 T[64][136];
    const int t = threadIdx.x;
    {
        const int sl = t >> 2, dc = (t & 3) * 32;
        const uint4* src = (const uint4*)(kvbf +
            ((size_t)(b * S_ + s0 + sl) * (2 * D_) + D_ + h * HD_ + dc));
        uint4 a0 = src[0], a1 = src[1], a2 = src[2], a3 = src[3];
        *(uint4*)&T[sl][dc]      = a0;
        *(uint4*)&T[sl][dc + 8]  = a1;
        *(uint4*)&T[sl][dc + 16] = a2;
        *(uint4*)&T[sl][dc + 24] = a3;
    }
    __syncthreads();
    {
        const int d = t >> 1, sh = (t & 1) * 32;
        union { u16 u[32]; uint4 q[4]; } buf;
#pragma unroll
        for (int i = 0; i < 32; ++i) buf.u[i] = T[sh + i][d];
        uint4* dst = (uint4*)(vt +
            ((size_t)((b * H_ + h) * HD_ + d)) * S_ + s0 + sh);
        dst[0] = buf.q[0]; dst[1] = buf.q[1];
        dst[2] = buf.q[2]; dst[3] = buf.q[3];
    }
}

// ---------------------------------------------------------------------------
// Split-K flash attention (bf16 MFMA, per-wave online softmax, barrier-free
// main loop). One block = 32 queries; 4 waves take key-tiles kt≡wave (mod 4),
// each with private (m,l,O). K/V fragments read directly from global (L2-hot,
// no LDS staging, no main-loop __syncthreads). End-of-block merge: m/l table
// in LDS, partial-O combined via LDS fp32 atomicAdd (ds_add_f32), then
// normalize + bf16 store.
// grid: 2048 blocks 1D, heavy (high-qt) blocks first.
// ---------------------------------------------------------------------------
#define PPITCH 40
#define OPITCH 132

__global__ __launch_bounds__(256)
void flash_attn_kernel(const u16* __restrict__ qbf, const u16* __restrict__ kvbf,
                       const u16* __restrict__ vt,
                       const unsigned char* __restrict__ mask,
                       u16* __restrict__ out) {
    const int x  = blockIdx.x;
    const int qt = (S_ / 32 - 1) - (x >> 5);   // heavy blocks dispatched first
    const int hb = x & 31;
    const int h  = hb >> 1, b = hb & 1;
    const int q0 = qt * 32;
    const int tid  = threadIdx.x;
    const int wave = tid >> 6, lane = tid & 63;
    const int l15  = lane & 15, g = lane >> 4;

    __shared__ __align__(16) u16 Pl[4][32][PPITCH];  // per-wave P round trip
    __shared__ float Ml[4][2][32];                   // per-wave m,l per row
    __shared__ float Of[32][OPITCH];                 // merged O (fp32)
    __shared__ float InvL[32];

    // zero the merge buffer (no barrier needed yet; covered by merge barrier)
    for (int t = tid; t < 32 * OPITCH; t += 256) ((float*)Of)[t] = 0.f;

    // Q fragments (A-operand), shared queries across all 4 waves
    bf16x8 qf[2][4];
#pragma unroll
    for (int qg = 0; qg < 2; ++qg)
#pragma unroll
        for (int c = 0; c < 4; ++c)
            qf[qg][c] = *(const bf16x8*)(qbf +
                (size_t)(b * S_ + q0 + qg * 16 + l15) * D_ +
                h * HD_ + c * 32 + g * 8);

    f32x4 o[2][8];
    float m_run[2][4], l_run[2][4];
#pragma unroll
    for (int qg = 0; qg < 2; ++qg) {
#pragma unroll
        for (int i = 0; i < 8; ++i) o[qg][i] = (f32x4)0.f;
#pragma unroll
        for (int r = 0; r < 4; ++r) { m_run[qg][r] = -INFINITY; l_run[qg][r] = 0.f; }
    }

    const u16* kbase = kvbf + (size_t)b * S_ * (2 * D_) + h * HD_;
    const u16* vbase = vt + (size_t)((b * H_ + h) * HD_) * S_;
    const int nt = qt + 1;   // 32-key tiles (causal)

    for (int kt = wave; kt < nt; kt += 4) {
        const int k0 = kt * 32;

        const unsigned char mv0 = mask[b * S_ + k0 + l15];
        const unsigned char mv1 = mask[b * S_ + k0 + 16 + l15];

        // K fragments (B-operand) straight from global
        bf16x8 kf0[4], kf1[4];
#pragma unroll
        for (int c = 0; c < 4; ++c) {
            kf0[c] = *(const bf16x8*)(kbase +
                (size_t)(k0 + l15) * (2 * D_) + c * 32 + g * 8);
            kf1[c] = *(const bf16x8*)(kbase +
                (size_t)(k0 + 16 + l15) * (2 * D_) + c * 32 + g * 8);
        }

#pragma unroll
        for (int qg = 0; qg < 2; ++qg) {
            f32x4 s0 = (f32x4)0.f, s1 = (f32x4)0.f;
#pragma unroll
            for (int c = 0; c < 4; ++c) {
                s0 = __builtin_amdgcn_mfma_f32_16x16x32_bf16(qf[qg][c], kf0[c], s0, 0, 0, 0);
                s1 = __builtin_amdgcn_mfma_f32_16x16x32_bf16(qf[qg][c], kf1[c], s1, 0, 0, 0);
            }
            const int qbase = q0 + qg * 16 + 4 * g;
            const int ka = k0 + l15, kb = k0 + 16 + l15;
#pragma unroll
            for (int r = 0; r < 4; ++r) {
                float v0 = s0[r] * SCALE, v1 = s1[r] * SCALE;
                if (ka > qbase + r || mv0) v0 = -INFINITY;
                if (kb > qbase + r || mv1) v1 = -INFINITY;
                s0[r] = v0; s1[r] = v1;
            }
            float tm[4];
#pragma unroll
            for (int r = 0; r < 4; ++r) tm[r] = fmaxf(s0[r], s1[r]);
#pragma unroll
            for (int off = 1; off < 16; off <<= 1)
#pragma unroll
                for (int r = 0; r < 4; ++r)
                    tm[r] = fmaxf(tm[r], __shfl_xor(tm[r], off));

            float alpha[4], ts[4];
#pragma unroll
            for (int r = 0; r < 4; ++r) {
                float nm = fmaxf(m_run[qg][r], tm[r]);
                alpha[r] = __expf(m_run[qg][r] - nm);
                m_run[qg][r] = nm;
                s0[r] = __expf(s0[r] - nm);
                s1[r] = __expf(s1[r] - nm);
                ts[r] = s0[r] + s1[r];
            }
#pragma unroll
            for (int off = 1; off < 16; off <<= 1)
#pragma unroll
                for (int r = 0; r < 4; ++r)
                    ts[r] += __shfl_xor(ts[r], off);
#pragma unroll
            for (int r = 0; r < 4; ++r)
                l_run[qg][r] = l_run[qg][r] * alpha[r] + ts[r];

            f32x4 av; av[0]=alpha[0]; av[1]=alpha[1]; av[2]=alpha[2]; av[3]=alpha[3];
#pragma unroll
            for (int i = 0; i < 8; ++i) o[qg][i] *= av;

#pragma unroll
            for (int r = 0; r < 4; ++r) {
                Pl[wave][qg * 16 + 4 * g + r][l15]      = f2bf(s0[r]);
                Pl[wave][qg * 16 + 4 * g + r][16 + l15] = f2bf(s1[r]);
            }
        }

        // PV: P (A-layout) from this wave's LDS slice, V fragments from global
        bf16x8 pf0 = *(const bf16x8*)&Pl[wave][l15][g * 8];
        bf16x8 pf1 = *(const bf16x8*)&Pl[wave][16 + l15][g * 8];
#pragma unroll
        for (int i = 0; i < 8; ++i) {
            bf16x8 vf = *(const bf16x8*)(vbase +
                (size_t)(16 * i + l15) * S_ + k0 + g * 8);
            o[0][i] = __builtin_amdgcn_mfma_f32_16x16x32_bf16(pf0, vf, o[0][i], 0, 0, 0);
            o[1][i] = __builtin_amdgcn_mfma_f32_16x16x32_bf16(pf1, vf, o[1][i], 0, 0, 0);
        }
    }

    // ---- merge the 4 per-wave partials ----
    if (l15 == 0) {
#pragma unroll
        for (int qg = 0; qg < 2; ++qg)
#pragma unroll
            for (int r = 0; r < 4; ++r) {
                Ml[wave][0][qg * 16 + 4 * g + r] = m_run[qg][r];
                Ml[wave][1][qg * 16 + 4 * g + r] = l_run[qg][r];
            }
    }
    __syncthreads();   // Ml complete + Of zeroing complete

    float beta[2][4];
#pragma unroll
    for (int qg = 0; qg < 2; ++qg)
#pragma unroll
        for (int r = 0; r < 4; ++r) {
            const int row = qg * 16 + 4 * g + r;
            const float m0 = Ml[0][0][row], m1 = Ml[1][0][row];
            const float m2 = Ml[2][0][row], m3 = Ml[3][0][row];
            const float mg = fmaxf(fmaxf(m0, m1), fmaxf(m2, m3));
            const float b0 = (m0 == -INFINITY) ? 0.f : __expf(m0 - mg);
            const float b1 = (m1 == -INFINITY) ? 0.f : __expf(m1 - mg);
            const float b2 = (m2 == -INFINITY) ? 0.f : __expf(m2 - mg);
            const float b3 = (m3 == -INFINITY) ? 0.f : __expf(m3 - mg);
            const float lg = b0 * Ml[0][1][row] + b1 * Ml[1][1][row] +
                             b2 * Ml[2][1][row] + b3 * Ml[3][1][row];
            beta[qg][r] = (m_run[qg][r] == -INFINITY)
                            ? 0.f : __expf(m_run[qg][r] - mg);
            if (wave == 0 && l15 == 0) InvL[row] = 1.f / lg;
        }

#pragma unroll
    for (int qg = 0; qg < 2; ++qg) {
        f32x4 bv; bv[0]=beta[qg][0]; bv[1]=beta[qg][1]; bv[2]=beta[qg][2]; bv[3]=beta[qg][3];
#pragma unroll
        for (int i = 0; i < 8; ++i) {
            f32x4 v = o[qg][i] * bv;
#pragma unroll
            for (int r = 0; r < 4; ++r)
                atomicAdd(&Of[qg * 16 + 4 * g + r][16 * i + l15], v[r]);
        }
    }
    __syncthreads();

    // write out: thread t -> row t>>3, 16-col segment (t&7)*16
    {
        const int row = tid >> 3, cseg = (tid & 7) * 16;
        const float inv = InvL[row];
        union { u16 u[16]; uint4 q[2]; } ob;
#pragma unroll
        for (int j = 0; j < 16; ++j) ob.u[j] = f2bf(Of[row][cseg + j] * inv);
        uint4* dst = (uint4*)(out +
            (size_t)(b * S_ + q0 + row) * D_ + h * HD_ + cseg);
        dst[0] = ob.q[0]; dst[1] = ob.q[1];
    }
}

// ---------------------------------------------------------------------------
extern "C" void kernel_launch(void* const* d_in, const int* in_sizes, int n_in,
                              void* d_out, int out_size, void* d_ws, size_t ws_size,
                              hipStream_t stream) {
    const float* x        = (const float*)d_in[0];
    const unsigned char* mask = (const unsigned char*)d_in[1];
    const float* wq_down  = (const float*)d_in[2];
    const float* bq_down  = (const float*)d_in[3];
    const float* gq_ln    = (const float*)d_in[4];
    const float* bq_ln    = (const float*)d_in[5];
    const float* wq_up    = (const float*)d_in[6];
    const float* bq_up    = (const float*)d_in[7];
    const float* wkv_down = (const float*)d_in[8];
    const float* bkv_down = (const float*)d_in[9];
    const float* gkv_ln   = (const float*)d_in[10];
    const float* bkv_ln   = (const float*)d_in[11];
    const float* wkv_up   = (const float*)d_in[12];
    const float* bkv_up   = (const float*)d_in[13];
    const float* w_out    = (const float*)d_in[14];
    const float* b_out    = (const float*)d_in[15];
    float* out = (float*)d_out;

    // Workspace layout (byte offsets, MB). Total 90 MB.
    char* ws = (char*)d_ws;
    u16* x_bf      = (u16*)(ws);
    u16* vt        = (u16*)(ws);
    u16* kv_lat_bf = (u16*)(ws + (16u << 20));
    u16* attn_bf   = (u16*)(ws + (16u << 20));
    u16* q_lat_bf  = (u16*)(ws + (20u << 20));
    u16* wkvd_t    = (u16*)(ws + (24u << 20));
    u16* wqd_t     = (u16*)(ws + (26u << 20));
    u16* wkvu_t    = (u16*)(ws + (28u << 20));
    u16* wqu_t     = (u16*)(ws + (32u << 20));
    u16* wout_t    = (u16*)(ws + (34u << 20));
    u16* q_bf      = (u16*)(ws + (42u << 20));
    u16* kv_bf     = (u16*)(ws + (58u << 20));

    const int M = B_ * S_;  // 4096
    dim3 blk(256);

    // casts / transposes
    cast_bf16_kernel<<<(M * D_ / 4 + 255) / 256, blk, 0, stream>>>(x, x_bf, M * D_ / 4);
    cast_transpose_kernel<<<dim3(L_ / 64, D_ / 64), blk, 0, stream>>>(wq_down,  wqd_t,  D_, L_);
    cast_transpose_kernel<<<dim3(D_ / 64, L_ / 64), blk, 0, stream>>>(wq_up,    wqu_t,  L_, D_);
    cast_transpose_kernel<<<dim3(L_ / 64, D_ / 64), blk, 0, stream>>>(wkv_down, wkvd_t, D_, L_);
    cast_transpose_kernel<<<dim3(2 * D_ / 64, L_ / 64), blk, 0, stream>>>(wkv_up, wkvu_t, L_, 2 * D_);
    cast_transpose_kernel<<<dim3(D_ / 64, D_ / 64), blk, 0, stream>>>(w_out,    wout_t, D_, D_);

    // KV path
    gemm_mfma_kernel<u16><<<dim3(L_ / 128, M / 128), blk, 0, stream>>>(
        x_bf, wkvd_t, bkv_down, kv_lat_bf, M, L_, D_);
    layernorm512_bf16_kernel<<<M, blk, 0, stream>>>(kv_lat_bf, gkv_ln, bkv_ln);
    gemm_mfma_kernel<u16><<<dim3(2 * D_ / 128, M / 128), blk, 0, stream>>>(
        kv_lat_bf, wkvu_t, bkv_up, kv_bf, M, 2 * D_, L_);

    // Q path
    gemm_mfma_kernel<u16><<<dim3(L_ / 128, M / 128), blk, 0, stream>>>(
        x_bf, wqd_t, bq_down, q_lat_bf, M, L_, D_);
    layernorm512_bf16_kernel<<<M, blk, 0, stream>>>(q_lat_bf, gq_ln, bq_ln);
    gemm_mfma_kernel<u16><<<dim3(D_ / 128, M / 128), blk, 0, stream>>>(
        q_lat_bf, wqu_t, bq_up, q_bf, M, D_, L_);

    // V transpose (x_bf dead; vt overlays it)
    vtrans_kernel<<<dim3(S_ / 64, H_, B_), blk, 0, stream>>>(kv_bf, vt);

    // Split-K flash attention -> bf16 attn
    flash_attn_kernel<<<dim3((S_ / 32) * H_ * B_), blk, 0, stream>>>(
        q_bf, kv_bf, vt, mask, attn_bf);

    // Output projection (fp32 out)
    gemm_mfma_kernel<float><<<dim3(D_ / 128, M / 128), blk, 0, stream>>>(
        attn_bf, wout_t, b_out, out, M, D_, D_);
}

// Round 5
// 607.964 us; speedup vs baseline: 10.8993x; 1.0664x over previous
//
#include <hip/hip_runtime.h>
#include <math.h>
#include <type_traits>

typedef unsigned short u16;
typedef __attribute__((ext_vector_type(8))) short bf16x8;
typedef __attribute__((ext_vector_type(4))) float f32x4;

// Problem constants (fixed by the reference)
#define B_  2
#define S_  2048
#define D_  2048
#define H_  16
#define HD_ 128
#define L_  512
constexpr float EPS   = 1e-5f;
constexpr float SCALE = 0.08838834764831845f; // 1/sqrt(128)

__device__ __forceinline__ u16 f2bf(float x) {
    unsigned u = __float_as_uint(x);
    u += 0x7fffu + ((u >> 16) & 1u);   // round-to-nearest-even
    return (u16)(u >> 16);
}
__device__ __forceinline__ float bf2f(u16 v) {
    return __uint_as_float(((unsigned)v) << 16);
}

// async global->LDS, 16 B per lane; LDS dest = lptr + lane*16 (wave-uniform base)
__device__ __forceinline__ void gl_lds16(const u16* g, u16* l) {
    __builtin_amdgcn_global_load_lds(
        (const __attribute__((address_space(1))) unsigned int*)g,
        (__attribute__((address_space(3))) unsigned int*)l, 16, 0, 0);
}

// ---------------------------------------------------------------------------
// bf16 MFMA GEMM (m97 structure): C[M,N] = A[M,K] @ Bt[N,K]^T + bias[N]
// 128x128 tile, BK=32, 256 thr, 4 waves x (64x64 via 4x4 mfma 16x16x32).
// ---------------------------------------------------------------------------
template <typename OutT>
__global__ __launch_bounds__(256)
void gemm_mfma_kernel(const u16* __restrict__ A, const u16* __restrict__ Bt,
                      const float* __restrict__ bias, OutT* __restrict__ C,
                      int M, int N, int K) {
    __shared__ __align__(16) u16 As[128 * 32];
    __shared__ __align__(16) u16 Bs[128 * 32];

    const int tid  = threadIdx.x;
    const int wave = tid >> 6, lane = tid & 63;
    const int l15  = lane & 15, g = lane >> 4;
    const int wm   = wave >> 1, wn = wave & 1;
    const int m0   = blockIdx.y * 128, n0 = blockIdx.x * 128;

    const int sr = lane >> 2;       // staging row within 16-row group
    const int sc = lane & 3;        // chunk slot
    const int swz = (l15 >> 1) & 3; // read-side swizzle key

    f32x4 acc[4][4];
#pragma unroll
    for (int i = 0; i < 4; ++i)
#pragma unroll
        for (int j = 0; j < 4; ++j) acc[i][j] = (f32x4)0.f;

    for (int k0 = 0; k0 < K; k0 += 32) {
#pragma unroll
        for (int t = 0; t < 2; ++t) {
            const int r  = wave * 32 + t * 16 + sr;
            const int c  = sc ^ ((r >> 1) & 3);
            gl_lds16(A  + (size_t)(m0 + r) * K + k0 + c * 8,
                     &As[(wave * 32 + t * 16) * 32]);
            gl_lds16(Bt + (size_t)(n0 + r) * K + k0 + c * 8,
                     &Bs[(wave * 32 + t * 16) * 32]);
        }
        __syncthreads();

        bf16x8 af[4], bfr[4];
#pragma unroll
        for (int i = 0; i < 4; ++i) {
            const int ra = wm * 64 + i * 16 + l15;
            af[i]  = *(const bf16x8*)&As[ra * 32 + (g ^ swz) * 8];
            const int rb = wn * 64 + i * 16 + l15;
            bfr[i] = *(const bf16x8*)&Bs[rb * 32 + (g ^ swz) * 8];
        }
#pragma unroll
        for (int i = 0; i < 4; ++i)
#pragma unroll
            for (int j = 0; j < 4; ++j)
                acc[i][j] = __builtin_amdgcn_mfma_f32_16x16x32_bf16(
                    af[i], bfr[j], acc[i][j], 0, 0, 0);
        __syncthreads();
    }

#pragma unroll
    for (int j = 0; j < 4; ++j) {
        const int n  = n0 + wn * 64 + j * 16 + l15;
        const float bv = bias[n];
#pragma unroll
        for (int i = 0; i < 4; ++i) {
            const int mb = m0 + wm * 64 + i * 16 + g * 4;
#pragma unroll
            for (int r = 0; r < 4; ++r) {
                float v = acc[i][j][r] + bv;
                if constexpr (std::is_same_v<OutT, float>)
                    C[(size_t)(mb + r) * N + n] = v;
                else
                    C[(size_t)(mb + r) * N + n] = f2bf(v);
            }
        }
    }
}

// ---------------------------------------------------------------------------
// fp32 -> bf16 cast
// ---------------------------------------------------------------------------
__global__ __launch_bounds__(256)
void cast_bf16_kernel(const float* __restrict__ src, u16* __restrict__ dst,
                      int n4) {
    const int i = blockIdx.x * 256 + threadIdx.x;
    if (i < n4) {
        float4 f = ((const float4*)src)[i];
        ushort4 o;
        o.x = f2bf(f.x); o.y = f2bf(f.y); o.z = f2bf(f.z); o.w = f2bf(f.w);
        ((ushort4*)dst)[i] = o;
    }
}

// ---------------------------------------------------------------------------
// fp32 W[K,N] -> bf16 Wt[N,K]
// ---------------------------------------------------------------------------
__global__ __launch_bounds__(256)
void cast_transpose_kernel(const float* __restrict__ W, u16* __restrict__ Wt,
                           int K, int N) {
    __shared__ u16 T[64][72];
    const int n0 = blockIdx.x * 64, k0 = blockIdx.y * 64;
    const int t  = threadIdx.x;
    {
        const int kr = t >> 2, nc = (t & 3) * 16;
#pragma unroll
        for (int v = 0; v < 4; ++v) {
            float4 f = *(const float4*)&W[(size_t)(k0 + kr) * N + n0 + nc + v * 4];
            T[nc + v * 4 + 0][kr] = f2bf(f.x);
            T[nc + v * 4 + 1][kr] = f2bf(f.y);
            T[nc + v * 4 + 2][kr] = f2bf(f.z);
            T[nc + v * 4 + 3][kr] = f2bf(f.w);
        }
    }
    __syncthreads();
    {
        const int nr = t >> 2, kc = (t & 3) * 16;
        union { u16 u[16]; uint4 q[2]; } o;
#pragma unroll
        for (int i = 0; i < 16; ++i) o.u[i] = T[nr][kc + i];
        uint4* dst = (uint4*)&Wt[(size_t)(n0 + nr) * K + k0 + kc];
        dst[0] = o.q[0]; dst[1] = o.q[1];
    }
}

// ---------------------------------------------------------------------------
// In-place bf16 row LayerNorm, rows of 512
// ---------------------------------------------------------------------------
__global__ __launch_bounds__(256)
void layernorm512_bf16_kernel(u16* __restrict__ buf, const float* __restrict__ g,
                              const float* __restrict__ bvec) {
    const int row = blockIdx.x;
    u16* p = buf + (size_t)row * L_;
    const int tid = threadIdx.x;

    float x0 = bf2f(p[tid]), x1 = bf2f(p[tid + 256]);
    float s  = x0 + x1;
    float sq = x0 * x0 + x1 * x1;

    __shared__ float red[8];
    __shared__ float stats[2];

#pragma unroll
    for (int off = 32; off; off >>= 1) {
        s  += __shfl_down(s, off);
        sq += __shfl_down(sq, off);
    }
    const int wave = tid >> 6;
    if ((tid & 63) == 0) { red[wave] = s; red[wave + 4] = sq; }
    __syncthreads();
    if (tid == 0) {
        float ts = red[0] + red[1] + red[2] + red[3];
        float tq = red[4] + red[5] + red[6] + red[7];
        float mean = ts / (float)L_;
        float var  = tq / (float)L_ - mean * mean;
        stats[0] = mean;
        stats[1] = rsqrtf(var + EPS);
    }
    __syncthreads();
    const float mean = stats[0], rstd = stats[1];
    p[tid]       = f2bf((x0 - mean) * rstd * g[tid]       + bvec[tid]);
    p[tid + 256] = f2bf((x1 - mean) * rstd * g[tid + 256] + bvec[tid + 256]);
}

// ---------------------------------------------------------------------------
// V transpose: vt[(b*H+h)*HD + d][s] = kv_bf[(b*S+s)*2D + D + h*HD + d]
// ---------------------------------------------------------------------------
__global__ __launch_bounds__(256)
void vtrans_kernel(const u16* __restrict__ kvbf, u16* __restrict__ vt) {
    const int s0 = blockIdx.x * 64;
    const int h  = blockIdx.y, b = blockIdx.z;
    __shared__ u16 T[64][136];
    const int t = threadIdx.x;
    {
        const int sl = t >> 2, dc = (t & 3) * 32;
        const uint4* src = (const uint4*)(kvbf +
            ((size_t)(b * S_ + s0 + sl) * (2 * D_) + D_ + h * HD_ + dc));
        uint4 a0 = src[0], a1 = src[1], a2 = src[2], a3 = src[3];
        *(uint4*)&T[sl][dc]      = a0;
        *(uint4*)&T[sl][dc + 8]  = a1;
        *(uint4*)&T[sl][dc + 16] = a2;
        *(uint4*)&T[sl][dc + 24] = a3;
    }
    __syncthreads();
    {
        const int d = t >> 1, sh = (t & 1) * 32;
        union { u16 u[32]; uint4 q[4]; } buf;
#pragma unroll
        for (int i = 0; i < 32; ++i) buf.u[i] = T[sh + i][d];
        uint4* dst = (uint4*)(vt +
            ((size_t)((b * H_ + h) * HD_ + d)) * S_ + s0 + sh);
        dst[0] = buf.q[0]; dst[1] = buf.q[1];
        dst[2] = buf.q[2]; dst[3] = buf.q[3];
    }
}

// ---------------------------------------------------------------------------
// Flash attention v3: 16 queries per WAVE, full causal K-range per wave,
// zero barriers, zero cross-wave state. 4 independent waves per block handle
// 4 consecutive 16-query tiles (work differs by <=1 k-tile). Per-wave online
// softmax with skip-rescale (O rescaled only when running max changes).
// K/V fragments straight from global (L2-hot). P round-trips through a
// private LDS slice for C-layout -> A-layout.
// grid: (S/64)*H*B = 1024 blocks, heavy q-groups first.
// ---------------------------------------------------------------------------
#define PPITCH 40

__global__ __launch_bounds__(256)
void flash_attn_kernel(const u16* __restrict__ qbf, const u16* __restrict__ kvbf,
                       const u16* __restrict__ vt,
                       const unsigned char* __restrict__ mask,
                       u16* __restrict__ out) {
    const int x    = blockIdx.x;
    const int qgrp = (S_ / 64 - 1) - (x >> 5);   // heavy blocks first
    const int hb   = x & 31;
    const int h    = hb >> 1, b = hb & 1;
    const int tid  = threadIdx.x;
    const int wave = tid >> 6, lane = tid & 63;
    const int l15  = lane & 15, g = lane >> 4;
    const int q0   = qgrp * 64 + wave * 16;      // this wave's 16 queries

    __shared__ __align__(16) u16 Pl[4][16][PPITCH];   // 5120 B, per-wave slice

    // Q fragments (A-operand): row l15, k = c*32 + g*8 + j
    bf16x8 qf[4];
#pragma unroll
    for (int c = 0; c < 4; ++c)
        qf[c] = *(const bf16x8*)(qbf +
            (size_t)(b * S_ + q0 + l15) * D_ + h * HD_ + c * 32 + g * 8);

    f32x4 o[8];
#pragma unroll
    for (int i = 0; i < 8; ++i) o[i] = (f32x4)0.f;
    float m_run[4], l_run[4];
#pragma unroll
    for (int r = 0; r < 4; ++r) { m_run[r] = -INFINITY; l_run[r] = 0.f; }

    const u16* kbase = kvbf + (size_t)b * S_ * (2 * D_) + h * HD_;
    const u16* vbase = vt + (size_t)((b * H_ + h) * HD_) * S_;
    const unsigned char* mbase = mask + b * S_;
    const int nt = ((q0 + 15) >> 5) + 1;   // 32-key causal tiles

    for (int kt = 0; kt < nt; ++kt) {
        const int k0 = kt * 32;

        const unsigned char mv0 = mbase[k0 + l15];
        const unsigned char mv1 = mbase[k0 + 16 + l15];

        // K fragments (B-operand) straight from global
        bf16x8 kf0[4], kf1[4];
#pragma unroll
        for (int c = 0; c < 4; ++c) {
            kf0[c] = *(const bf16x8*)(kbase +
                (size_t)(k0 + l15) * (2 * D_) + c * 32 + g * 8);
            kf1[c] = *(const bf16x8*)(kbase +
                (size_t)(k0 + 16 + l15) * (2 * D_) + c * 32 + g * 8);
        }

        f32x4 s0 = (f32x4)0.f, s1 = (f32x4)0.f;
#pragma unroll
        for (int c = 0; c < 4; ++c) {
            s0 = __builtin_amdgcn_mfma_f32_16x16x32_bf16(qf[c], kf0[c], s0, 0, 0, 0);
            s1 = __builtin_amdgcn_mfma_f32_16x16x32_bf16(qf[c], kf1[c], s1, 0, 0, 0);
        }

        // scale + causal/padding mask: row q = q0 + 4g + r, keys k0+l15 / +16
        const int qb = q0 + 4 * g;
        const int ka = k0 + l15, kb = k0 + 16 + l15;
#pragma unroll
        for (int r = 0; r < 4; ++r) {
            float v0 = s0[r] * SCALE, v1 = s1[r] * SCALE;
            if (ka > qb + r || mv0) v0 = -INFINITY;
            if (kb > qb + r || mv1) v1 = -INFINITY;
            s0[r] = v0; s1[r] = v1;
        }

        // row max across the 16 key-columns
        float tm[4];
#pragma unroll
        for (int r = 0; r < 4; ++r) tm[r] = fmaxf(s0[r], s1[r]);
#pragma unroll
        for (int off = 1; off < 16; off <<= 1)
#pragma unroll
            for (int r = 0; r < 4; ++r)
                tm[r] = fmaxf(tm[r], __shfl_xor(tm[r], off));

        float nm[4];
        bool chg = false;
#pragma unroll
        for (int r = 0; r < 4; ++r) {
            nm[r] = fmaxf(m_run[r], tm[r]);
            chg |= (nm[r] > m_run[r]);
        }
        if (__any(chg)) {   // wave-uniform: rescale only when max moved
            f32x4 av;
#pragma unroll
            for (int r = 0; r < 4; ++r) {
                const float a = __expf(m_run[r] - nm[r]);
                av[r] = a;
                l_run[r] *= a;
                m_run[r] = nm[r];
            }
#pragma unroll
            for (int i = 0; i < 8; ++i) o[i] *= av;
        }

        float ts[4];
#pragma unroll
        for (int r = 0; r < 4; ++r) {
            s0[r] = __expf(s0[r] - m_run[r]);
            s1[r] = __expf(s1[r] - m_run[r]);
            ts[r] = s0[r] + s1[r];
        }
#pragma unroll
        for (int off = 1; off < 16; off <<= 1)
#pragma unroll
            for (int r = 0; r < 4; ++r)
                ts[r] += __shfl_xor(ts[r], off);
#pragma unroll
        for (int r = 0; r < 4; ++r) l_run[r] += ts[r];

        // P: C-layout -> LDS -> A-layout (one bf16x8 covers all 32 keys)
#pragma unroll
        for (int r = 0; r < 4; ++r) {
            Pl[wave][4 * g + r][l15]      = f2bf(s0[r]);
            Pl[wave][4 * g + r][16 + l15] = f2bf(s1[r]);
        }
        const bf16x8 pf = *(const bf16x8*)&Pl[wave][l15][g * 8];

        // PV: V fragments (B-operand) from global vt
#pragma unroll
        for (int i = 0; i < 8; ++i) {
            bf16x8 vf = *(const bf16x8*)(vbase +
                (size_t)(16 * i + l15) * S_ + k0 + g * 8);
            o[i] = __builtin_amdgcn_mfma_f32_16x16x32_bf16(pf, vf, o[i], 0, 0, 0);
        }
    }

    // epilogue: normalize + bf16 store (wave-private rows)
    float inv[4];
#pragma unroll
    for (int r = 0; r < 4; ++r) inv[r] = 1.0f / l_run[r];
#pragma unroll
    for (int i = 0; i < 8; ++i)
#pragma unroll
        for (int r = 0; r < 4; ++r)
            out[(size_t)(b * S_ + q0 + 4 * g + r) * D_ +
                h * HD_ + 16 * i + l15] = f2bf(o[i][r] * inv[r]);
}

// ---------------------------------------------------------------------------
extern "C" void kernel_launch(void* const* d_in, const int* in_sizes, int n_in,
                              void* d_out, int out_size, void* d_ws, size_t ws_size,
                              hipStream_t stream) {
    const float* x        = (const float*)d_in[0];
    const unsigned char* mask = (const unsigned char*)d_in[1];
    const float* wq_down  = (const float*)d_in[2];
    const float* bq_down  = (const float*)d_in[3];
    const float* gq_ln    = (const float*)d_in[4];
    const float* bq_ln    = (const float*)d_in[5];
    const float* wq_up    = (const float*)d_in[6];
    const float* bq_up    = (const float*)d_in[7];
    const float* wkv_down = (const float*)d_in[8];
    const float* bkv_down = (const float*)d_in[9];
    const float* gkv_ln   = (const float*)d_in[10];
    const float* bkv_ln   = (const float*)d_in[11];
    const float* wkv_up   = (const float*)d_in[12];
    const float* bkv_up   = (const float*)d_in[13];
    const float* w_out    = (const float*)d_in[14];
    const float* b_out    = (const float*)d_in[15];
    float* out = (float*)d_out;

    // Workspace layout (byte offsets, MB). Total 90 MB.
    char* ws = (char*)d_ws;
    u16* x_bf      = (u16*)(ws);
    u16* vt        = (u16*)(ws);
    u16* kv_lat_bf = (u16*)(ws + (16u << 20));
    u16* attn_bf   = (u16*)(ws + (16u << 20));
    u16* q_lat_bf  = (u16*)(ws + (20u << 20));
    u16* wkvd_t    = (u16*)(ws + (24u << 20));
    u16* wqd_t     = (u16*)(ws + (26u << 20));
    u16* wkvu_t    = (u16*)(ws + (28u << 20));
    u16* wqu_t     = (u16*)(ws + (32u << 20));
    u16* wout_t    = (u16*)(ws + (34u << 20));
    u16* q_bf      = (u16*)(ws + (42u << 20));
    u16* kv_bf     = (u16*)(ws + (58u << 20));

    const int M = B_ * S_;  // 4096
    dim3 blk(256);

    // casts / transposes
    cast_bf16_kernel<<<(M * D_ / 4 + 255) / 256, blk, 0, stream>>>(x, x_bf, M * D_ / 4);
    cast_transpose_kernel<<<dim3(L_ / 64, D_ / 64), blk, 0, stream>>>(wq_down,  wqd_t,  D_, L_);
    cast_transpose_kernel<<<dim3(D_ / 64, L_ / 64), blk, 0, stream>>>(wq_up,    wqu_t,  L_, D_);
    cast_transpose_kernel<<<dim3(L_ / 64, D_ / 64), blk, 0, stream>>>(wkv_down, wkvd_t, D_, L_);
    cast_transpose_kernel<<<dim3(2 * D_ / 64, L_ / 64), blk, 0, stream>>>(wkv_up, wkvu_t, L_, 2 * D_);
    cast_transpose_kernel<<<dim3(D_ / 64, D_ / 64), blk, 0, stream>>>(w_out,    wout_t, D_, D_);

    // KV path
    gemm_mfma_kernel<u16><<<dim3(L_ / 128, M / 128), blk, 0, stream>>>(
        x_bf, wkvd_t, bkv_down, kv_lat_bf, M, L_, D_);
    layernorm512_bf16_kernel<<<M, blk, 0, stream>>>(kv_lat_bf, gkv_ln, bkv_ln);
    gemm_mfma_kernel<u16><<<dim3(2 * D_ / 128, M / 128), blk, 0, stream>>>(
        kv_lat_bf, wkvu_t, bkv_up, kv_bf, M, 2 * D_, L_);

    // Q path
    gemm_mfma_kernel<u16><<<dim3(L_ / 128, M / 128), blk, 0, stream>>>(
        x_bf, wqd_t, bq_down, q_lat_bf, M, L_, D_);
    layernorm512_bf16_kernel<<<M, blk, 0, stream>>>(q_lat_bf, gq_ln, bq_ln);
    gemm_mfma_kernel<u16><<<dim3(D_ / 128, M / 128), blk, 0, stream>>>(
        q_lat_bf, wqu_t, bq_up, q_bf, M, D_, L_);

    // V transpose (x_bf dead; vt overlays it)
    vtrans_kernel<<<dim3(S_ / 64, H_, B_), blk, 0, stream>>>(kv_bf, vt);

    // Flash attention v3 -> bf16 attn
    flash_attn_kernel<<<dim3((S_ / 64) * H_ * B_), blk, 0, stream>>>(
        q_bf, kv_bf, vt, mask, attn_bf);

    // Output projection (fp32 out)
    gemm_mfma_kernel<float><<<dim3(D_ / 128, M / 128), blk, 0, stream>>>(
        attn_bf, wout_t, b_out, out, M, D_, D_);
}